// Round 4
// baseline (284.107 us; speedup 1.0000x reference)
//
#include <hip/hip_runtime.h>

// ---------------------------------------------------------------------------
// TemporalHyperedge: loss[b] = 0.2 * sum_n ||cur[b]@r_proj - W@pre[b]||_2
//                              + sum_n (max_m W[n,m] + 0.001*||W[n,:]||_2)
// W = incidence_m masked to > 0.01. Output = [loss(32) , incidence_m(2048^2)].
//
// R3 changes:
//  - gemm: BK=64 (half the barrier drains), 32x32x16 MFMA (faster pipe,
//    m119: 2495 vs 2075 TF), cur staged as f32 + in-kernel bf16 convert
//    (removes the 96 MB curb prep pass entirely).
//  - prep transpose: write-transposed LDS (pitch 68 -> conflict-free scalar
//    writes), vectorized ushort4 LDS reads + ushort8 global stores.
// ---------------------------------------------------------------------------

typedef __attribute__((ext_vector_type(8))) short bf16x8;
typedef __attribute__((ext_vector_type(8))) unsigned short ushort8;
typedef __attribute__((ext_vector_type(16))) float f32x16;

__device__ __forceinline__ unsigned short f2bf(float f) {
    union { float f; unsigned u; } x; x.f = f;
    unsigned r = x.u + 0x7fffu + ((x.u >> 16) & 1u);   // RNE
    return (unsigned short)(r >> 16);
}

#define GLL16(g, l)                                                         \
    __builtin_amdgcn_global_load_lds(                                       \
        (const __attribute__((address_space(1))) void*)(g),                 \
        (__attribute__((address_space(3))) void*)(l), 16, 0, 0)

// --------------------------------------------------------------------------
// transpose_64x64: src f32 (R,C) tile (r0,c0) -> dst bf16 (C,R).
// Write-transposed into LDS (pitch 68 shorts: addr = (fc)*68+m covers all 64
// residues mod 64 -> conflict-free scalar writes). Reads: 4x ushort4 per lane
// (8B aligned, ~4-way even-bank), stores 2x ushort8 (16B) coalesced.
// --------------------------------------------------------------------------
__device__ __forceinline__ void transpose_64x64(
    const float* __restrict__ src, unsigned short* __restrict__ dst,
    int R, int C, int r0, int c0, unsigned short* __restrict__ tile) {
    const int t = threadIdx.x;
    const int fr = t >> 4, fc = (t & 15) * 4;
#pragma unroll
    for (int it = 0; it < 4; ++it) {
        int m = fr + it * 16;
        float4 v = *(const float4*)(src + (size_t)(r0 + m) * C + c0 + fc);
        tile[(fc + 0) * 68 + m] = f2bf(v.x);
        tile[(fc + 1) * 68 + m] = f2bf(v.y);
        tile[(fc + 2) * 68 + m] = f2bf(v.z);
        tile[(fc + 3) * 68 + m] = f2bf(v.w);
    }
    __syncthreads();
    const int d = t >> 2, m0 = (t & 3) * 16;
    unsigned short v[16];
#pragma unroll
    for (int j = 0; j < 4; ++j)
        *(ushort4*)(v + j * 4) = *(const ushort4*)(tile + d * 68 + m0 + j * 4);
    unsigned short* dp = dst + (size_t)(c0 + d) * R + r0 + m0;
    ushort8 p0, p1;
#pragma unroll
    for (int j = 0; j < 8; ++j) { p0[j] = v[j]; p1[j] = v[8 + j]; }
    *(ushort8*)(dp) = p0;
    *(ushort8*)(dp + 8) = p1;
}

// --------------------------------------------------------------------------
// prep_all — block sections:
//   [0,2048)    : incidence row: copy-out, -masked bf16 W, crow[row]=l1+1e-3*l2
//   [2048,6144) : pre (32,2048,256) -> preT (32,256,2048) bf16 transpose
//   [6144,6160) : r_proj (256,256) -> rprojT bf16 transpose
// (cur is no longer converted here — gemm stages it f32 and converts in LDS)
// --------------------------------------------------------------------------
__global__ __launch_bounds__(256) void prep_all(
    const float* __restrict__ inc, float* __restrict__ out_inc,
    unsigned short* __restrict__ Wneg, float* __restrict__ crow,
    const float* __restrict__ pre, unsigned short* __restrict__ preT,
    const float* __restrict__ r_proj, unsigned short* __restrict__ rprojT) {
    __shared__ unsigned short tile[64 * 68];
    __shared__ float smax[4], ssum[4];
    const int bid = blockIdx.x;
    const int t = threadIdx.x;

    if (bid < 2048) {
        const int row = bid;
        const float4* src = (const float4*)(inc + (size_t)row * 2048);
        float4* dst = (float4*)(out_inc + (size_t)row * 2048);
        ushort4* wp = (ushort4*)(Wneg + (size_t)row * 2048);
        float lmax = 0.f, ss = 0.f;
#pragma unroll
        for (int it = 0; it < 2; ++it) {
            int i = it * 256 + t;
            float4 v = src[i];
            dst[i] = v;
            float w0 = v.x > 0.01f ? v.x : 0.f;
            float w1 = v.y > 0.01f ? v.y : 0.f;
            float w2 = v.z > 0.01f ? v.z : 0.f;
            float w3 = v.w > 0.01f ? v.w : 0.f;
            ushort4 p;
            p.x = f2bf(-w0); p.y = f2bf(-w1); p.z = f2bf(-w2); p.w = f2bf(-w3);
            wp[i] = p;
            lmax = fmaxf(lmax, fmaxf(fmaxf(w0, w1), fmaxf(w2, w3)));
            ss += w0 * w0 + w1 * w1 + w2 * w2 + w3 * w3;
        }
#pragma unroll
        for (int off = 32; off; off >>= 1) {
            lmax = fmaxf(lmax, __shfl_down(lmax, off));
            ss += __shfl_down(ss, off);
        }
        int wv = t >> 6, ln = t & 63;
        if (ln == 0) { smax[wv] = lmax; ssum[wv] = ss; }
        __syncthreads();
        if (t == 0) {
            float m = fmaxf(fmaxf(smax[0], smax[1]), fmaxf(smax[2], smax[3]));
            float s = ssum[0] + ssum[1] + ssum[2] + ssum[3];
            crow[row] = m + 0.001f * sqrtf(s);
        }
    } else if (bid < 6144) {
        const int tt = bid - 2048;
        const int b = tt >> 7;             // 32 batches
        const int mt = (tt & 127) >> 2;    // 32 m-tiles
        const int dt = tt & 3;             // 4 d-tiles
        transpose_64x64(pre + (size_t)b * 524288, preT + (size_t)b * 524288,
                        2048, 256, mt * 64, dt * 64, tile);
    } else {
        const int tt = bid - 6144;
        transpose_64x64(r_proj, rprojT, 256, 256, (tt >> 2) * 64, (tt & 3) * 64,
                        tile);
    }
}

// --------------------------------------------------------------------------
// gemm_diff: block = 128n x 256d (full D), BK=64, K=2304 (36 k-tiles:
// 32 of W|preT + 4 of cur(f32, converted in-kernel)|rprojT).
// 256 threads = 4 waves 2x2 (wm: 64n halves, wn: 128d halves); each wave
// 2x4 grid of 32x32x16 MFMAs x 4 k-steps = 32 MFMA per barrier.
// Epilogue: sum_d diff^2 -> Ssq[b,n] = sqrt(.), plain store (block owns rows).
// --------------------------------------------------------------------------
__global__ __launch_bounds__(256, 2) void gemm_diff(
    const unsigned short* __restrict__ Wneg,    // (2048,2048) bf16, negated+masked
    const float* __restrict__ cur,              // (32,2048,256) f32
    const unsigned short* __restrict__ preT,    // (32,256,2048) bf16
    const unsigned short* __restrict__ rprojT,  // (256,256) bf16
    float* __restrict__ Ssq)                    // (32,2048)
{
    const int n0 = blockIdx.x * 128;
    const int b  = blockIdx.y;

    __shared__ unsigned short Al[128 * 64];   // 16 KB
    __shared__ unsigned short Bl[256 * 64];   // 32 KB
    __shared__ float ssq[128];

    const int tid  = threadIdx.x;
    const int w    = tid >> 6;
    const int lane = tid & 63;
    const int l32  = lane & 31;
    const int half = lane >> 5;
    const int wm   = w >> 1, wn = w & 1;

    if (tid < 128) ssq[tid] = 0.f;

    f32x16 acc[2][4] = {};

    const float*          curB = cur  + (size_t)b * 2048 * 256;
    const unsigned short* preB = preT + (size_t)b * 256 * 2048;

    const int grow  = lane >> 3;        // 0..7  (rows within a GLL16 call)
    const int gbyte = (lane & 7) * 16;  // bytes within a 128B row

    for (int kt = 0; kt < 36; ++kt) {
        __syncthreads();  // previous tile fully consumed
        if (kt < 32) {
            const int k0 = kt * 64;
            // A: Wneg rows n0+w*32.., 128B per row, 4 GLL16 (8 rows each)
            const unsigned short* ab = Wneg + (size_t)n0 * 2048 + k0;
#pragma unroll
            for (int j = 0; j < 4; ++j) {
                const int row = w * 32 + j * 8 + grow;
                GLL16((const char*)(ab + (size_t)row * 2048) + gbyte,
                      (char*)Al + w * 4096 + j * 1024);
            }
            // B: preT d-rows w*64.., 8 GLL16
            const unsigned short* bb = preB + k0;
#pragma unroll
            for (int j = 0; j < 8; ++j) {
                const int row = w * 64 + j * 8 + grow;
                GLL16((const char*)(bb + (size_t)row * 2048) + gbyte,
                      (char*)Bl + w * 8192 + j * 1024);
            }
        } else {
            const int kk = kt * 64 - 2048;
            // A from cur f32: load+convert+ds_write (conflict-free banks)
            const int r16 = tid >> 4, k4 = tid & 15;
#pragma unroll
            for (int i = 0; i < 8; ++i) {
                const int row = r16 + i * 16;
                float4 v = *(const float4*)(curB + (size_t)(n0 + row) * 256 + kk + k4 * 4);
                ushort4 p;
                p.x = f2bf(v.x); p.y = f2bf(v.y); p.z = f2bf(v.z); p.w = f2bf(v.w);
                *(ushort4*)(Al + row * 64 + k4 * 4) = p;
            }
            // B from rprojT
            const unsigned short* bb = rprojT + kk;
#pragma unroll
            for (int j = 0; j < 8; ++j) {
                const int row = w * 64 + j * 8 + grow;
                GLL16((const char*)(bb + (size_t)row * 256) + gbyte,
                      (char*)Bl + w * 8192 + j * 1024);
            }
        }
        __syncthreads();  // staging visible

#pragma unroll
        for (int ks = 0; ks < 4; ++ks) {
            bf16x8 af[2], bfr[4];
#pragma unroll
            for (int mi = 0; mi < 2; ++mi)
                af[mi] = *(const bf16x8*)(Al + (wm * 64 + mi * 32 + l32) * 64 +
                                          ks * 16 + half * 8);
#pragma unroll
            for (int ni = 0; ni < 4; ++ni)
                bfr[ni] = *(const bf16x8*)(Bl + (wn * 128 + ni * 32 + l32) * 64 +
                                           ks * 16 + half * 8);
#pragma unroll
            for (int mi = 0; mi < 2; ++mi)
#pragma unroll
                for (int ni = 0; ni < 4; ++ni)
                    acc[mi][ni] = __builtin_amdgcn_mfma_f32_32x32x16_bf16(
                        af[mi], bfr[ni], acc[mi][ni], 0, 0, 0);
        }
    }
    __syncthreads();

    // 32x32 C/D layout: col(d)=lane&31, row(n)=(reg&3)+8*(reg>>2)+4*half
    // [verified m74/m101]
#pragma unroll
    for (int mi = 0; mi < 2; ++mi)
#pragma unroll
        for (int reg = 0; reg < 16; ++reg) {
            float s = 0.f;
#pragma unroll
            for (int ni = 0; ni < 4; ++ni) {
                float v = acc[mi][ni][reg];
                s += v * v;
            }
            s += __shfl_xor(s, 1);
            s += __shfl_xor(s, 2);
            s += __shfl_xor(s, 4);
            s += __shfl_xor(s, 8);
            s += __shfl_xor(s, 16);
            if (l32 == 0) {
                const int row = (reg & 3) + 8 * (reg >> 2) + 4 * half;
                atomicAdd(&ssq[wm * 64 + mi * 32 + row], s);  // 2-way (wn)
            }
        }
    __syncthreads();
    if (tid < 128)
        Ssq[(size_t)b * 2048 + n0 + tid] = sqrtf(ssq[tid]);
}

// --------------------------------------------------------------------------
// finalize: loss[b] = 0.2 * sum_n Ssq[b,n] + sum_n crow[n]
// --------------------------------------------------------------------------
__global__ void finalize(const float* __restrict__ Ssq,
                         const float* __restrict__ crow,
                         float* __restrict__ out) {
    const int b = blockIdx.x;
    float s1 = 0.f, s2 = 0.f;
    for (int i = threadIdx.x; i < 2048; i += 256) {
        s1 += Ssq[(size_t)b * 2048 + i];
        s2 += crow[i];
    }
#pragma unroll
    for (int off = 32; off; off >>= 1) {
        s1 += __shfl_down(s1, off);
        s2 += __shfl_down(s2, off);
    }
    __shared__ float sm1[4], sm2[4];
    int wv = threadIdx.x >> 6, ln = threadIdx.x & 63;
    if (ln == 0) { sm1[wv] = s1; sm2[wv] = s2; }
    __syncthreads();
    if (threadIdx.x == 0)
        out[b] = 0.2f * (sm1[0] + sm1[1] + sm1[2] + sm1[3])
               + (sm2[0] + sm2[1] + sm2[2] + sm2[3]);
}

// --------------------------------------------------------------------------
extern "C" void kernel_launch(void* const* d_in, const int* in_sizes, int n_in,
                              void* d_out, int out_size, void* d_ws, size_t ws_size,
                              hipStream_t stream) {
    const float* cur    = (const float*)d_in[0];  // (32,2048,256)
    const float* pre    = (const float*)d_in[1];  // (32,2048,256)
    const float* r_proj = (const float*)d_in[2];  // (256,256)
    const float* inc    = (const float*)d_in[3];  // (2048,2048)
    float* out = (float*)d_out;                   // [0..31]=loss, [32..]=incidence

    char* ws = (char*)d_ws;
    unsigned short* Wneg   = (unsigned short*)(ws + 0);          //  8 MB
    unsigned short* preT   = (unsigned short*)(ws + 8388608);    // 32 MB
    unsigned short* rprojT = (unsigned short*)(ws + 41943040);   // 128 KB
    float*          Sbuf   = (float*)(ws + 42074112);            // 256 KB
    float*          crow   = (float*)(ws + 42336256);            // 8 KB

    prep_all<<<6160, 256, 0, stream>>>(inc, out + 32, Wneg, crow,
                                       pre, preT, r_proj, rprojT);
    gemm_diff<<<dim3(16, 32), 256, 0, stream>>>(Wneg, cur, preT, rprojT, Sbuf);
    finalize<<<32, 256, 0, stream>>>(Sbuf, crow, out);
}

// Round 5
// 247.724 us; speedup vs baseline: 1.1469x; 1.1469x over previous
//
#include <hip/hip_runtime.h>

// ---------------------------------------------------------------------------
// TemporalHyperedge: loss[b] = 0.2 * sum_n ||cur[b]@r_proj - W@pre[b]||_2
//                              + sum_n (max_m W[n,m] + 0.001*||W[n,:]||_2)
// W = incidence_m masked to > 0.01. Output = [loss(32) , incidence_m(2048^2)].
//
// R4 change: XOR chunk-swizzle on the gemm LDS tiles. R3's BK=64 made the
// LDS row stride 128B = 32 banks, so every ds_read_b128 phase was 8-way
// bank-conflicted (SQ_LDS_BANK_CONFLICT 7.1M -> 49.6M). We permute the
// SOURCE chunk per lane in the global_load_lds staging (LDS[r][p] =
// G[r][p^(r&7)]) and XOR the fragment-read chunk index accordingly -> each
// 8-lane phase covers all 8 bank-quads, conflict-free. Everything else kept.
// ---------------------------------------------------------------------------

typedef __attribute__((ext_vector_type(8))) short bf16x8;
typedef __attribute__((ext_vector_type(8))) unsigned short ushort8;
typedef __attribute__((ext_vector_type(16))) float f32x16;

__device__ __forceinline__ unsigned short f2bf(float f) {
    union { float f; unsigned u; } x; x.f = f;
    unsigned r = x.u + 0x7fffu + ((x.u >> 16) & 1u);   // RNE
    return (unsigned short)(r >> 16);
}

#define GLL16(g, l)                                                         \
    __builtin_amdgcn_global_load_lds(                                       \
        (const __attribute__((address_space(1))) void*)(g),                 \
        (__attribute__((address_space(3))) void*)(l), 16, 0, 0)

// --------------------------------------------------------------------------
// transpose_64x64: src f32 (R,C) tile (r0,c0) -> dst bf16 (C,R).
// --------------------------------------------------------------------------
__device__ __forceinline__ void transpose_64x64(
    const float* __restrict__ src, unsigned short* __restrict__ dst,
    int R, int C, int r0, int c0, unsigned short* __restrict__ tile) {
    const int t = threadIdx.x;
    const int fr = t >> 4, fc = (t & 15) * 4;
#pragma unroll
    for (int it = 0; it < 4; ++it) {
        int m = fr + it * 16;
        float4 v = *(const float4*)(src + (size_t)(r0 + m) * C + c0 + fc);
        tile[(fc + 0) * 68 + m] = f2bf(v.x);
        tile[(fc + 1) * 68 + m] = f2bf(v.y);
        tile[(fc + 2) * 68 + m] = f2bf(v.z);
        tile[(fc + 3) * 68 + m] = f2bf(v.w);
    }
    __syncthreads();
    const int d = t >> 2, m0 = (t & 3) * 16;
    unsigned short v[16];
#pragma unroll
    for (int j = 0; j < 4; ++j)
        *(ushort4*)(v + j * 4) = *(const ushort4*)(tile + d * 68 + m0 + j * 4);
    unsigned short* dp = dst + (size_t)(c0 + d) * R + r0 + m0;
    ushort8 p0, p1;
#pragma unroll
    for (int j = 0; j < 8; ++j) { p0[j] = v[j]; p1[j] = v[8 + j]; }
    *(ushort8*)(dp) = p0;
    *(ushort8*)(dp + 8) = p1;
}

// --------------------------------------------------------------------------
// prep_all — block sections:
//   [0,2048)    : incidence row: copy-out, -masked bf16 W, crow[row]=l1+1e-3*l2
//   [2048,6144) : pre (32,2048,256) -> preT (32,256,2048) bf16 transpose
//   [6144,6160) : r_proj (256,256) -> rprojT bf16 transpose
// --------------------------------------------------------------------------
__global__ __launch_bounds__(256) void prep_all(
    const float* __restrict__ inc, float* __restrict__ out_inc,
    unsigned short* __restrict__ Wneg, float* __restrict__ crow,
    const float* __restrict__ pre, unsigned short* __restrict__ preT,
    const float* __restrict__ r_proj, unsigned short* __restrict__ rprojT) {
    __shared__ unsigned short tile[64 * 68];
    __shared__ float smax[4], ssum[4];
    const int bid = blockIdx.x;
    const int t = threadIdx.x;

    if (bid < 2048) {
        const int row = bid;
        const float4* src = (const float4*)(inc + (size_t)row * 2048);
        float4* dst = (float4*)(out_inc + (size_t)row * 2048);
        ushort4* wp = (ushort4*)(Wneg + (size_t)row * 2048);
        float lmax = 0.f, ss = 0.f;
#pragma unroll
        for (int it = 0; it < 2; ++it) {
            int i = it * 256 + t;
            float4 v = src[i];
            dst[i] = v;
            float w0 = v.x > 0.01f ? v.x : 0.f;
            float w1 = v.y > 0.01f ? v.y : 0.f;
            float w2 = v.z > 0.01f ? v.z : 0.f;
            float w3 = v.w > 0.01f ? v.w : 0.f;
            ushort4 p;
            p.x = f2bf(-w0); p.y = f2bf(-w1); p.z = f2bf(-w2); p.w = f2bf(-w3);
            wp[i] = p;
            lmax = fmaxf(lmax, fmaxf(fmaxf(w0, w1), fmaxf(w2, w3)));
            ss += w0 * w0 + w1 * w1 + w2 * w2 + w3 * w3;
        }
#pragma unroll
        for (int off = 32; off; off >>= 1) {
            lmax = fmaxf(lmax, __shfl_down(lmax, off));
            ss += __shfl_down(ss, off);
        }
        int wv = t >> 6, ln = t & 63;
        if (ln == 0) { smax[wv] = lmax; ssum[wv] = ss; }
        __syncthreads();
        if (t == 0) {
            float m = fmaxf(fmaxf(smax[0], smax[1]), fmaxf(smax[2], smax[3]));
            float s = ssum[0] + ssum[1] + ssum[2] + ssum[3];
            crow[row] = m + 0.001f * sqrtf(s);
        }
    } else if (bid < 6144) {
        const int tt = bid - 2048;
        const int b = tt >> 7;
        const int mt = (tt & 127) >> 2;
        const int dt = tt & 3;
        transpose_64x64(pre + (size_t)b * 524288, preT + (size_t)b * 524288,
                        2048, 256, mt * 64, dt * 64, tile);
    } else {
        const int tt = bid - 6144;
        transpose_64x64(r_proj, rprojT, 256, 256, (tt >> 2) * 64, (tt & 3) * 64,
                        tile);
    }
}

// --------------------------------------------------------------------------
// gemm_diff: block = 128n x 256d, BK=64, K=2304. 32x32x16 MFMA, 4 waves 2x2.
// LDS tiles chunk-swizzled: LDS[r][p] = G[r][p ^ (r&7)]  (p = 16B chunk idx).
// --------------------------------------------------------------------------
__global__ __launch_bounds__(256, 2) void gemm_diff(
    const unsigned short* __restrict__ Wneg,    // (2048,2048) bf16 neg+masked
    const float* __restrict__ cur,              // (32,2048,256) f32
    const unsigned short* __restrict__ preT,    // (32,256,2048) bf16
    const unsigned short* __restrict__ rprojT,  // (256,256) bf16
    float* __restrict__ Ssq)                    // (32,2048)
{
    const int n0 = blockIdx.x * 128;
    const int b  = blockIdx.y;

    __shared__ unsigned short Al[128 * 64];   // 16 KB
    __shared__ unsigned short Bl[256 * 64];   // 32 KB
    __shared__ float ssq[128];

    const int tid  = threadIdx.x;
    const int w    = tid >> 6;
    const int lane = tid & 63;
    const int l32  = lane & 31;
    const int half = lane >> 5;
    const int wm   = w >> 1, wn = w & 1;

    if (tid < 128) ssq[tid] = 0.f;

    f32x16 acc[2][4] = {};

    const float*          curB = cur  + (size_t)b * 2048 * 256;
    const unsigned short* preB = preT + (size_t)b * 256 * 2048;

    const int grow  = lane >> 3;                    // 0..7 row-within-chunk
    const int gbyte = ((lane & 7) ^ grow) * 16;     // SWIZZLED source chunk
    const int sw    = (l32 & 7) * 8;                // fragment-read swizzle base

    for (int kt = 0; kt < 36; ++kt) {
        __syncthreads();  // previous tile fully consumed
        if (kt < 32) {
            const int k0 = kt * 64;
            const unsigned short* ab = Wneg + (size_t)n0 * 2048 + k0;
#pragma unroll
            for (int j = 0; j < 4; ++j) {
                const int row = w * 32 + j * 8 + grow;
                GLL16((const char*)(ab + (size_t)row * 2048) + gbyte,
                      (char*)Al + w * 4096 + j * 1024);
            }
            const unsigned short* bb = preB + k0;
#pragma unroll
            for (int j = 0; j < 8; ++j) {
                const int row = w * 64 + j * 8 + grow;
                GLL16((const char*)(bb + (size_t)row * 2048) + gbyte,
                      (char*)Bl + w * 8192 + j * 1024);
            }
        } else {
            const int kk = kt * 64 - 2048;
            // A from cur f32: load+convert+ds_write, swizzled chunk position
            const int r16 = tid >> 4, k4 = tid & 15;
#pragma unroll
            for (int i = 0; i < 8; ++i) {
                const int row = r16 + i * 16;
                float4 v = *(const float4*)(curB + (size_t)(n0 + row) * 256 + kk + k4 * 4);
                ushort4 p;
                p.x = f2bf(v.x); p.y = f2bf(v.y); p.z = f2bf(v.z); p.w = f2bf(v.w);
                const int pos = ((k4 >> 1) ^ (row & 7)) * 8 + (k4 & 1) * 4;
                *(ushort4*)(Al + row * 64 + pos) = p;
            }
            const unsigned short* bb = rprojT + kk;
#pragma unroll
            for (int j = 0; j < 8; ++j) {
                const int row = w * 64 + j * 8 + grow;
                GLL16((const char*)(bb + (size_t)row * 256) + gbyte,
                      (char*)Bl + w * 8192 + j * 1024);
            }
        }
        __syncthreads();  // staging visible

#pragma unroll
        for (int ks = 0; ks < 4; ++ks) {
            const int ck = (ks * 2 + half) * 8;
            bf16x8 af[2], bfr[4];
#pragma unroll
            for (int mi = 0; mi < 2; ++mi)
                af[mi] = *(const bf16x8*)(Al + (wm * 64 + mi * 32 + l32) * 64 +
                                          (ck ^ sw));
#pragma unroll
            for (int ni = 0; ni < 4; ++ni)
                bfr[ni] = *(const bf16x8*)(Bl + (wn * 128 + ni * 32 + l32) * 64 +
                                           (ck ^ sw));
#pragma unroll
            for (int mi = 0; mi < 2; ++mi)
#pragma unroll
                for (int ni = 0; ni < 4; ++ni)
                    acc[mi][ni] = __builtin_amdgcn_mfma_f32_32x32x16_bf16(
                        af[mi], bfr[ni], acc[mi][ni], 0, 0, 0);
        }
    }
    __syncthreads();

    // 32x32 C/D layout: col(d)=lane&31, row(n)=(reg&3)+8*(reg>>2)+4*half
#pragma unroll
    for (int mi = 0; mi < 2; ++mi)
#pragma unroll
        for (int reg = 0; reg < 16; ++reg) {
            float s = 0.f;
#pragma unroll
            for (int ni = 0; ni < 4; ++ni) {
                float v = acc[mi][ni][reg];
                s += v * v;
            }
            s += __shfl_xor(s, 1);
            s += __shfl_xor(s, 2);
            s += __shfl_xor(s, 4);
            s += __shfl_xor(s, 8);
            s += __shfl_xor(s, 16);
            if (l32 == 0) {
                const int row = (reg & 3) + 8 * (reg >> 2) + 4 * half;
                atomicAdd(&ssq[wm * 64 + mi * 32 + row], s);  // 2-way (wn)
            }
        }
    __syncthreads();
    if (tid < 128)
        Ssq[(size_t)b * 2048 + n0 + tid] = sqrtf(ssq[tid]);
}

// --------------------------------------------------------------------------
// finalize: loss[b] = 0.2 * sum_n Ssq[b,n] + sum_n crow[n]
// --------------------------------------------------------------------------
__global__ void finalize(const float* __restrict__ Ssq,
                         const float* __restrict__ crow,
                         float* __restrict__ out) {
    const int b = blockIdx.x;
    float s1 = 0.f, s2 = 0.f;
    for (int i = threadIdx.x; i < 2048; i += 256) {
        s1 += Ssq[(size_t)b * 2048 + i];
        s2 += crow[i];
    }
#pragma unroll
    for (int off = 32; off; off >>= 1) {
        s1 += __shfl_down(s1, off);
        s2 += __shfl_down(s2, off);
    }
    __shared__ float sm1[4], sm2[4];
    int wv = threadIdx.x >> 6, ln = threadIdx.x & 63;
    if (ln == 0) { sm1[wv] = s1; sm2[wv] = s2; }
    __syncthreads();
    if (threadIdx.x == 0)
        out[b] = 0.2f * (sm1[0] + sm1[1] + sm1[2] + sm1[3])
               + (sm2[0] + sm2[1] + sm2[2] + sm2[3]);
}

// --------------------------------------------------------------------------
extern "C" void kernel_launch(void* const* d_in, const int* in_sizes, int n_in,
                              void* d_out, int out_size, void* d_ws, size_t ws_size,
                              hipStream_t stream) {
    const float* cur    = (const float*)d_in[0];  // (32,2048,256)
    const float* pre    = (const float*)d_in[1];  // (32,2048,256)
    const float* r_proj = (const float*)d_in[2];  // (256,256)
    const float* inc    = (const float*)d_in[3];  // (2048,2048)
    float* out = (float*)d_out;                   // [0..31]=loss, [32..]=incidence

    char* ws = (char*)d_ws;
    unsigned short* Wneg   = (unsigned short*)(ws + 0);          //  8 MB
    unsigned short* preT   = (unsigned short*)(ws + 8388608);    // 32 MB
    unsigned short* rprojT = (unsigned short*)(ws + 41943040);   // 128 KB
    float*          Sbuf   = (float*)(ws + 42074112);            // 256 KB
    float*          crow   = (float*)(ws + 42336256);            // 8 KB

    prep_all<<<6160, 256, 0, stream>>>(inc, out + 32, Wneg, crow,
                                       pre, preT, r_proj, rprojT);
    gemm_diff<<<dim3(16, 32), 256, 0, stream>>>(Wneg, cur, preT, rprojT, Sbuf);
    finalize<<<32, 256, 0, stream>>>(Sbuf, crow, out);
}